// Round 6
// baseline (157.263 us; speedup 1.0000x reference)
//
#include <hip/hip_runtime.h>
#include <stdint.h>

// Problem constants (from reference)
#define B_SZ   512
#define T_SZ   100
#define NPRE   256
#define NPOST  256
#define KTOT   (B_SZ * T_SZ)   // 51200

typedef __bf16 bf16x8 __attribute__((ext_vector_type(8)));
typedef float  floatx4 __attribute__((ext_vector_type(4)));

__device__ __forceinline__ uint32_t bf16_rne(float v) {
    uint32_t bits = __float_as_uint(v);
    return (bits + 0x7FFFu + ((bits >> 16) & 1u)) >> 16;
}
__device__ __forceinline__ uint32_t pack_trunc2(float a, float b) {
    return (__float_as_uint(a) >> 16) | (__float_as_uint(b) & 0xFFFF0000u);
}

// ---------------------------------------------------------------------------
// R17: 4 barrier-groups per CU (the one variable that has tracked perf).
// Evidence (R10-R16): fused time ~ 87us/(independent barrier-groups per CU):
// 1 group = 52.9-87 (R13/R16), 2 groups = 43.5 (R10). All other levers
// (waves, load width, DMA pipeline, sched hints) were neutral-to-negative.
// Mechanism = m97/m114: a co-resident block's loads/MFMA cover another
// block's barrier drain; in-block pipelining cannot (m99/m131-141).
//
// 1024 blocks x 256 thr (4 waves). Block bx: s2 = bx&255 (batches 2s2,
// 2s2+1), tile = bx>>8: pt = tile&1 (p-half), qt = tile>>1 (q-half); C tile
// 128p x 128q. Quadrant blocks of s2 differ by 256 -> same XCD (mod 8),
// pre/post re-reads L2-served.
//
// Per block 4 phases: (b,h) in (0,0),(0,1),(1,0),(1,1); K-half = 64 t.
// LDS = A[16][512] + B[16][512] = 32 KB (single K-half buffer, R10's proven
// fragment layout per half). Waves with bh==b scan-deposit A (carry in reg
// across the b-phases; bit-identical fp32+RNE sequence, incremental uint4
// deposit -> no pk[50] array -> VGPR <= 128); the other 2 waves stage B
// (R10's exact pack, trunc exact for {0,1}); barrier; 2 kc x 16 MFMA;
// barrier.  Occupancy: LDS 32 KB -> 5 blocks/CU, VGPR<=128 (waves_per_eu
// (4,4)) -> 16 waves/CU -> 4 blocks/CU resident = 4 barrier groups.
// partial[bx][128][128] = 67 MB; reduce1 sums 256 s2-blocks.
// ---------------------------------------------------------------------------
__global__ __launch_bounds__(256) __attribute__((amdgpu_waves_per_eu(4, 4)))
void stdp_fused_gemm(
    const float* __restrict__ pre, const float* __restrict__ post,
    float* __restrict__ partial)
{
    __shared__ __align__(16) unsigned short A_lds[16][512];  // 16 KB
    __shared__ __align__(16) unsigned short B_lds[16][512];  // 16 KB

    const int bx   = blockIdx.x;      // 0..1023
    const int s2   = bx & 255;
    const int tile = bx >> 8;         // 0..3
    const int pt   = tile & 1;
    const int qt   = tile >> 1;
    const int tid  = threadIdx.x;     // 0..255
    const int lane = tid & 63, wave = tid >> 6;   // wave = wp (0..3)
    const int l15 = lane & 15, l4 = lane >> 4;

    const int bh   = tid >> 7;        // 0/1 (wave-uniform): which batch I scan
    const int nloc = tid & 127;       // my p (scan) / q (B-stage) column
    const int ng = nloc >> 4, n15 = nloc & 15;

    const float decay = 0.95122942450071400910f;   // expf(-1/20)

    float carry = 0.0f;
    floatx4 acc[2][8] = {};

#pragma unroll
    for (int ph = 0; ph < 4; ++ph) {
        const int b = ph >> 1, h = ph & 1;        // batch-in-block, K-half
        const int bglob = 2 * s2 + b;

        if (bh == b) {
            // ---- A scan-deposit: column p = pt*128 + nloc, t = h*64.. ----
            if (h == 0) carry = 0.0f;
            const float* src = pre + (size_t)bglob * (T_SZ * NPRE)
                                   + pt * 128 + nloc;
#pragma unroll
            for (int kc2 = 0; kc2 < 2; ++kc2) {
                if (h == 0 || kc2 == 0) {
                    // full 32-t chunk: t = h*64 + kc2*32 .. +31
                    float x[32];
#pragma unroll
                    for (int j = 0; j < 32; ++j)
                        x[j] = src[(size_t)(h * 64 + kc2 * 32 + j) * NPRE];
#pragma unroll
                    for (int w = 0; w < 4; ++w) {
                        uint32_t u[4];
#pragma unroll
                        for (int m = 0; m < 4; ++m) {
                            uint32_t lo = bf16_rne(carry);   // trace[t]=carry
                            carry = decay * (carry + x[w * 8 + 2 * m]);
                            uint32_t hi = bf16_rne(carry);
                            carry = decay * (carry + x[w * 8 + 2 * m + 1]);
                            u[m] = lo | (hi << 16);
                        }
                        *(uint4*)&A_lds[kc2 * 8 + ng][(w * 16 + n15) * 8] =
                            make_uint4(u[0], u[1], u[2], u[3]);
                    }
                } else {
                    // h==1, kc2==1: t 96..99 real, rest zero
                    float x[4];
#pragma unroll
                    for (int j = 0; j < 4; ++j)
                        x[j] = src[(size_t)(96 + j) * NPRE];
                    uint32_t u0, u1;
                    {
                        uint32_t lo = bf16_rne(carry);
                        carry = decay * (carry + x[0]);
                        uint32_t hi = bf16_rne(carry);
                        carry = decay * (carry + x[1]);
                        u0 = lo | (hi << 16);
                    }
                    {
                        uint32_t lo = bf16_rne(carry);
                        carry = decay * (carry + x[2]);
                        uint32_t hi = bf16_rne(carry);
                        carry = decay * (carry + x[3]);
                        u1 = lo | (hi << 16);
                    }
                    *(uint4*)&A_lds[8 + ng][n15 * 8] = make_uint4(u0, u1, 0u, 0u);
#pragma unroll
                    for (int w = 1; w < 4; ++w)
                        *(uint4*)&A_lds[8 + ng][(w * 16 + n15) * 8] =
                            make_uint4(0u, 0u, 0u, 0u);
                }
            }
        } else {
            // ---- B stage: column q = qt*128 + nloc, t = h*64.. ----
            const float* pb = post + (size_t)bglob * (T_SZ * NPOST)
                                   + qt * 128 + nloc;
#pragma unroll
            for (int kc2 = 0; kc2 < 2; ++kc2) {
                if (h == 0 || kc2 == 0) {
                    float y[32];
#pragma unroll
                    for (int j = 0; j < 32; ++j)
                        y[j] = pb[(size_t)(h * 64 + kc2 * 32 + j) * NPOST];
#pragma unroll
                    for (int w = 0; w < 4; ++w) {
                        uint32_t u[4];
#pragma unroll
                        for (int m = 0; m < 4; ++m)
                            u[m] = pack_trunc2(y[w * 8 + 2 * m],
                                               y[w * 8 + 2 * m + 1]);
                        *(uint4*)&B_lds[kc2 * 8 + ng][(w * 16 + n15) * 8] =
                            make_uint4(u[0], u[1], u[2], u[3]);
                    }
                } else {
                    float y[4];
#pragma unroll
                    for (int j = 0; j < 4; ++j)
                        y[j] = pb[(size_t)(96 + j) * NPOST];
                    *(uint4*)&B_lds[8 + ng][n15 * 8] =
                        make_uint4(pack_trunc2(y[0], y[1]),
                                   pack_trunc2(y[2], y[3]), 0u, 0u);
#pragma unroll
                    for (int w = 1; w < 4; ++w)
                        *(uint4*)&B_lds[8 + ng][(w * 16 + n15) * 8] =
                            make_uint4(0u, 0u, 0u, 0u);
                }
            }
        }
        __syncthreads();

        // ---- MFMA on the K-half: 2 kc x 16; wave wp covers 32p x 128q ----
#pragma unroll
        for (int kc = 0; kc < 2; ++kc) {
            bf16x8 a[2], bb[8];
#pragma unroll
            for (int f = 0; f < 2; ++f)
                a[f] = *(const bf16x8*)&A_lds[kc * 8 + wave * 2 + f][lane * 8];
#pragma unroll
            for (int g = 0; g < 8; ++g)
                bb[g] = *(const bf16x8*)&B_lds[kc * 8 + g][lane * 8];
#pragma unroll
            for (int f = 0; f < 2; ++f)
#pragma unroll
                for (int g = 0; g < 8; ++g)
                    acc[f][g] = __builtin_amdgcn_mfma_f32_16x16x32_bf16(
                        a[f], bb[g], acc[f][g], 0, 0, 0);
        }
        __syncthreads();
    }

    // ---- writeout: partial[bx][p_loc 128][q_loc 128]
    // C/D layout (m89/m91): col = lane&15, row = (lane>>4)*4 + reg
    float* pout = partial + (size_t)bx * (128 * 128);
#pragma unroll
    for (int f = 0; f < 2; ++f) {
        int r0 = wave * 32 + f * 16 + l4 * 4;
#pragma unroll
        for (int g = 0; g < 8; ++g) {
            int c = g * 16 + l15;
#pragma unroll
            for (int v = 0; v < 4; ++v)
                pout[(size_t)(r0 + v) * 128 + c] = acc[f][g][v];
        }
    }
}

// ---------------------------------------------------------------------------
// Reduce stage 1: partial[bx = tile*256 + s2][i], i = p*128+q.
// 2048 blocks x 256 thr; thread t: g = t>>16 (0..7), e = t&65535,
// tile = e>>14; sums s2 = g*32 .. g*32+31 (4 indep chains of 8).
// ---------------------------------------------------------------------------
__global__ __launch_bounds__(256) void stdp_reduce1(
    const float* __restrict__ partial, float* __restrict__ tmp)
{
    const int t = blockIdx.x * 256 + threadIdx.x;  // 0..524287
    const int g = t >> 16;                         // 0..7
    const int e = t & 65535;
    const int tile = e >> 14;
    const float* src = partial + ((size_t)(tile * 256 + g * 32) << 14) + (e & 16383);
    float a4[4] = {};
#pragma unroll
    for (int i = 0; i < 8; ++i)
#pragma unroll
        for (int u = 0; u < 4; ++u)
            a4[u] += src[(size_t)(u * 8 + i) << 14];
    tmp[t] = (a4[0] + a4[1]) + (a4[2] + a4[3]);
}

// ---------------------------------------------------------------------------
// Reduce stage 2 (R10-proven): 8 -> 1, un-tile, scale by (A+ - A-)/(B*T).
// ---------------------------------------------------------------------------
__global__ __launch_bounds__(256) void stdp_reduce2(
    const float* __restrict__ tmp, float* __restrict__ out)
{
    const int idx = blockIdx.x * 256 + threadIdx.x;  // 0..65535
    const int P = idx >> 8, Q = idx & 255;
    const int tile = (Q >> 7) * 2 + (P >> 7);
    const int e = (tile << 14) | ((P & 127) << 7) | (Q & 127);
    float a[4];
#pragma unroll
    for (int u = 0; u < 4; ++u)
        a[u] = tmp[(size_t)(2 * u) * 65536 + e] +
               tmp[(size_t)(2 * u + 1) * 65536 + e];
    const float scale = (0.005f - 0.00525f) * (1.0f / (float)KTOT);
    out[idx] = ((a[0] + a[1]) + (a[2] + a[3])) * scale;
}

// ---------------------------------------------------------------------------
extern "C" void kernel_launch(void* const* d_in, const int* in_sizes, int n_in,
                              void* d_out, int out_size, void* d_ws, size_t ws_size,
                              hipStream_t stream)
{
    const float* pre  = (const float*)d_in[0];   // [512,100,256]
    const float* post = (const float*)d_in[1];   // [512,100,256]
    float* out = (float*)d_out;                  // [256,256]

    // ws: partial 67 MB | tmp 2 MB
    float* partial = (float*)d_ws;
    float* tmp     = (float*)((char*)d_ws + (size_t)67108864);

    stdp_fused_gemm<<<1024, 256, 0, stream>>>(pre, post, partial);
    stdp_reduce1<<<2048, 256, 0, stream>>>(partial, tmp);
    stdp_reduce2<<<256, 256, 0, stream>>>(tmp, out);
}